// Round 22
// baseline (109.640 us; speedup 1.0000x reference)
//
#include <hip/hip_runtime.h>
#include <hip/hip_bf16.h>

typedef __attribute__((ext_vector_type(8))) short bf16x8;
typedef __attribute__((ext_vector_type(4))) short s16x4;
typedef __attribute__((ext_vector_type(4))) float f32x4;

__device__ __forceinline__ short f2bf(float f) {
    unsigned int u = __builtin_bit_cast(unsigned int, f);
    u += 0x7fffu + ((u >> 16) & 1u);
    return (short)(u >> 16);
}

#define GLDS(g, l) __builtin_amdgcn_global_load_lds( \
    (__attribute__((address_space(1))) void*)(g),    \
    (__attribute__((address_space(3))) void*)(l), 16, 0, 0)

#define BARSB() { __builtin_amdgcn_s_barrier(); __builtin_amdgcn_sched_barrier(0); }
#define VMC8()  { asm volatile("s_waitcnt vmcnt(8)" ::: "memory"); __builtin_amdgcn_sched_barrier(0); }
#define VMC7()  { asm volatile("s_waitcnt vmcnt(7)" ::: "memory"); __builtin_amdgcn_sched_barrier(0); }
#define VMC0()  { asm volatile("s_waitcnt vmcnt(0)" ::: "memory"); __builtin_amdgcn_sched_barrier(0); }

// ------ fused fp32->bf16 convert (x, wQKV, wOut) + cos/sin float2 table build --------
__global__ __launch_bounds__(256) void cvt_fused(const float* __restrict__ x,
                                                 const float* __restrict__ wq,
                                                 const float* __restrict__ wo,
                                                 const float* __restrict__ cosT,
                                                 const float* __restrict__ sinT,
                                                 short* __restrict__ xb,
                                                 short* __restrict__ wqb,
                                                 short* __restrict__ wob,
                                                 float2* __restrict__ csT) {
    const int b = blockIdx.x;
    if (b >= 8192) {
        const int idx = (b - 8192) * 256 + threadIdx.x;   // 0..65535
        const int i2 = idx >> 11;
        const int s = idx & 2047;
        csT[idx] = make_float2(cosT[s * 32 + i2], sinT[s * 32 + i2]);
        return;
    }
    const float* in; short* out; int i;
    if (b < 4096)      { in = x;  out = xb;  i = b * 256 + threadIdx.x; }
    else if (b < 7168) { in = wq; out = wqb; i = (b - 4096) * 256 + threadIdx.x; }
    else               { in = wo; out = wob; i = (b - 7168) * 256 + threadIdx.x; }
    float4 v = reinterpret_cast<const float4*>(in)[i];
    s16x4 r = { f2bf(v.x), f2bf(v.y), f2bf(v.z), f2bf(v.w) };
    reinterpret_cast<s16x4*>(out)[i] = r;
}

#define LDP 72

// ---------------- QKV GEMM (+RoPE), 256x192, loose-wave VMC7 ---------
__device__ __forceinline__ void load_a(const short* __restrict__ A, int wr, int lo, int hi,
                                       int mh, bf16x8 aF[4][2]) {
#pragma unroll
    for (int mi = 0; mi < 4; ++mi)
#pragma unroll
        for (int kk = 0; kk < 2; ++kk)
            aF[mi][kk] = *reinterpret_cast<const bf16x8*>(
                &A[(wr * 128 + mh * 64 + mi * 16 + lo) * 64 + (((kk * 4 + hi) ^ (lo & 7)) << 3)]);
}
__device__ __forceinline__ void load_b3(const short* __restrict__ B, int wc, int lo, int hi,
                                        bf16x8 bF[3][2]) {
#pragma unroll
    for (int ni = 0; ni < 3; ++ni)
#pragma unroll
        for (int kk = 0; kk < 2; ++kk)
            bF[ni][kk] = *reinterpret_cast<const bf16x8*>(
                &B[(wc * 48 + ni * 16 + lo) * 64 + (((kk * 4 + hi) ^ (lo & 7)) << 3)]);
}
__device__ __forceinline__ void mfma24(const bf16x8 aF[4][2], const bf16x8 bF[3][2],
                                       f32x4 acc[8][3], int mh) {
#pragma unroll
    for (int mi = 0; mi < 4; ++mi)
#pragma unroll
        for (int ni = 0; ni < 3; ++ni)
#pragma unroll
            for (int kk = 0; kk < 2; ++kk)
                acc[mh * 4 + mi][ni] = __builtin_amdgcn_mfma_f32_16x16x32_bf16(
                    aF[mi][kk], bF[ni][kk], acc[mh * 4 + mi][ni], 0, 0, 0);
}

__global__ __launch_bounds__(512, 1) void gemm_qkv_rope(
    const short* __restrict__ X, const short* __restrict__ W,
    const float2* __restrict__ csT,
    short* __restrict__ Qo, short* __restrict__ Ko, short* __restrict__ Vo) {
    __shared__ short ldsA[2][16384];
    __shared__ short ldsB[2][12288];
    const int tid = threadIdx.x;
    const int lane = tid & 63;
    const int w = tid >> 6;
    const int lo = lane & 15, hi = lane >> 4;
    const int wr = w >> 2, wc = w & 3;
    const int lin = blockIdx.x;
    const int xcd = lin & 7;
    const int i_ = lin >> 3;
    const int m0 = ((xcd >> 1) * 4 + (i_ & 3)) * 256;
    const int n0 = ((xcd & 1) * 8 + (i_ >> 2)) * 192;

    f32x4 acc[8][3];
#pragma unroll
    for (int i = 0; i < 8; i++)
#pragma unroll
        for (int j = 0; j < 3; j++) acc[i][j] = {0.f, 0.f, 0.f, 0.f};

    const int srow8 = w * 8 + (lane >> 3);
    const int scx = (((lane & 7) ^ ((lane >> 3) & 7)) << 3);

#define STAGE_A(BUF, KT, IT) GLDS(X + (size_t)(m0 + (IT) * 64 + srow8) * 1024 + ((KT) << 6) + scx, \
                                  (char*)&ldsA[BUF][0] + (IT) * 8192 + w * 1024)
#define STAGE_B(BUF, KT, IT) GLDS(W + (size_t)(n0 + (IT) * 64 + srow8) * 1024 + ((KT) << 6) + scx, \
                                  (char*)&ldsB[BUF][0] + (IT) * 8192 + w * 1024)

    bf16x8 aF[4][2], bF[3][2];

    STAGE_B(0, 0, 0); STAGE_B(0, 0, 1); STAGE_B(0, 0, 2);
    STAGE_A(0, 0, 0); STAGE_A(0, 0, 1); STAGE_A(0, 0, 2); STAGE_A(0, 0, 3);

    for (int t = 0; t < 16; ++t) {
        const int c = t & 1;
        if (t < 15) {
            const int nb_ = c ^ 1, t1 = t + 1;
            STAGE_B(nb_, t1, 0); STAGE_B(nb_, t1, 1); STAGE_B(nb_, t1, 2);
            STAGE_A(nb_, t1, 0); STAGE_A(nb_, t1, 1); STAGE_A(nb_, t1, 2); STAGE_A(nb_, t1, 3);
            VMC7();
        } else {
            VMC0();
        }
        BARSB();
        load_a(&ldsA[c][0], wr, lo, hi, 0, aF);
        load_b3(&ldsB[c][0], wc, lo, hi, bF);
        mfma24(aF, bF, acc, 0);
        load_a(&ldsA[c][0], wr, lo, hi, 1, aF);
        mfma24(aF, bF, acc, 1);
        if (t < 15) BARSB();
    }
#undef STAGE_A
#undef STAGE_B

    // ---- RoPE epilogue with coalesced float2 cos/sin table ----
    const int sfull = m0 + wr * 128 + (hi << 2);
    const int b_ = sfull >> 11;
    const int srow_ = sfull & 2047;
#pragma unroll
    for (int ni = 0; ni < 3; ni++) {
        const int n = n0 + wc * 48 + ni * 16 + lo;
        const int region = n >> 10;
        const int c = n & 1023;
        const int h = c >> 6;
        const int d = c & 63;
        const size_t obase = ((size_t)(b_ * 16 + h) * 2048 + srow_) * 64 + d;
        if (region == 2) {
#pragma unroll
            for (int mi = 0; mi < 8; mi++)
#pragma unroll
                for (int r = 0; r < 4; r++)
                    Vo[obase + (size_t)(mi * 16 + r) * 64] = f2bf(acc[mi][ni][r]);
        } else {
            short* dst = (region == 0) ? Qo : Ko;
            const float scale = (region == 0) ? 0.18033688f : 1.0f;  // 1/8 * log2(e)
            const float2* csrow = csT + (size_t)(d >> 1) * 2048 + srow_;
#pragma unroll
            for (int mi = 0; mi < 8; mi++) {
                float4 t0 = *reinterpret_cast<const float4*>(csrow + mi * 16);
                float4 t1 = *reinterpret_cast<const float4*>(csrow + mi * 16 + 2);
                const float cs_[4] = {t0.x, t0.z, t1.x, t1.z};
                const float sn_[4] = {t0.y, t0.w, t1.y, t1.w};
#pragma unroll
                for (int r = 0; r < 4; r++) {
                    float v = acc[mi][ni][r];
                    float other = __shfl_xor(v, 1, 64);
                    float outv = (d & 1) ? (v * cs_[r] + other * sn_[r])
                                         : (v * cs_[r] - other * sn_[r]);
                    dst[obase + (size_t)(mi * 16 + r) * 64] = f2bf(outv * scale);
                }
            }
        }
    }
}

// ---------------- Flash attention (single-buffer K/V -> 26KB LDS, 4 blocks/CU) -------
__device__ __forceinline__ void attn_tile_compute(
    const bf16x8 q0, const bf16x8 q1,
    const short* __restrict__ Ks,          // [64*64] chunk-XOR swizzled
    const short (*Vts)[LDP], short* __restrict__ Pw,
    const int lane, const int w, const bool diag,
    float& m_r, float& l_r, f32x4* __restrict__ o_acc) {
    const int lo = lane & 15, hi = lane >> 4;
    const int sx = lo & 7;

    f32x4 sc[4];
#pragma unroll
    for (int nb = 0; nb < 4; nb++) sc[nb] = {0.f, 0.f, 0.f, 0.f};
#pragma unroll
    for (int nb = 0; nb < 4; nb++) {
        const short* kr = &Ks[(nb * 16 + lo) * 64];
        bf16x8 k0 = *reinterpret_cast<const bf16x8*>(&kr[(hi ^ sx) << 3]);
        sc[nb] = __builtin_amdgcn_mfma_f32_16x16x32_bf16(k0, q0, sc[nb], 0, 0, 0);
        bf16x8 k1 = *reinterpret_cast<const bf16x8*>(&kr[((4 + hi) ^ sx) << 3]);
        sc[nb] = __builtin_amdgcn_mfma_f32_16x16x32_bf16(k1, q1, sc[nb], 0, 0, 0);
    }
    if (diag) {
        const int q_ = w * 16 + lo;
        const int kb = (hi << 2);
#pragma unroll
        for (int nb = 0; nb < 4; nb++) {
            const int k_ = nb * 16 + kb;
#pragma unroll
            for (int r = 0; r < 4; r++)
                if (k_ + r > q_) sc[nb][r] = -1e30f;
        }
    }

    float mx = sc[0][0];
#pragma unroll
    for (int nb = 0; nb < 4; nb++)
#pragma unroll
        for (int r = 0; r < 4; r++) mx = fmaxf(mx, sc[nb][r]);
    mx = fmaxf(mx, __shfl_xor(mx, 16, 64));
    mx = fmaxf(mx, __shfl_xor(mx, 32, 64));

    if (!__all(mx <= m_r + 8.0f)) {
        const float mnew = fmaxf(m_r, mx);
        const float alpha = __builtin_amdgcn_exp2f(m_r - mnew);
        m_r = mnew;
        l_r *= alpha;
        float aq[4];
#pragma unroll
        for (int r = 0; r < 4; r++) aq[r] = __shfl(alpha, (hi << 2) + r, 64);
#pragma unroll
        for (int db = 0; db < 4; db++)
#pragma unroll
            for (int r = 0; r < 4; r++) o_acc[db][r] *= aq[r];
    }

    float rs = 0.f;
#pragma unroll
    for (int nb = 0; nb < 4; nb++)
#pragma unroll
        for (int r = 0; r < 4; r++) {
            float e = __builtin_amdgcn_exp2f(sc[nb][r] - m_r);
            sc[nb][r] = e;
            rs += e;
        }
    rs += __shfl_xor(rs, 16, 64);
    rs += __shfl_xor(rs, 32, 64);
    l_r += rs;

    unsigned int* Pw32 = reinterpret_cast<unsigned int*>(Pw);
#pragma unroll
    for (int nb = 0; nb < 4; nb++)
#pragma unroll
        for (int rr = 0; rr < 2; rr++) {
            unsigned int pk;
            asm("v_cvt_pk_bf16_f32 %0, %1, %2"
                : "=v"(pk) : "v"(sc[nb][2 * rr]), "v"(sc[nb][2 * rr + 1]));
            Pw32[lo * (LDP / 2) + nb * 8 + (hi << 1) + rr] = pk;
        }

#pragma unroll
    for (int kk = 0; kk < 2; kk++) {
        bf16x8 pa = *reinterpret_cast<const bf16x8*>(&Pw[lo * LDP + kk * 32 + hi * 8]);
#pragma unroll
        for (int db = 0; db < 4; db++) {
            const int d = db * 16 + lo;
            const int tsw = (kk * 32 + hi * 8) ^ ((((d >> 3) & 7)) << 3);
            bf16x8 vb = *reinterpret_cast<const bf16x8*>(&Vts[d][tsw]);
            o_acc[db] = __builtin_amdgcn_mfma_f32_16x16x32_bf16(pa, vb, o_acc[db], 0, 0, 0);
        }
    }
}

__global__ __launch_bounds__(256) void attn_kernel(
    const short* __restrict__ Q, const short* __restrict__ K,
    const short* __restrict__ V, short* __restrict__ O) {
    __shared__ short Ks[64 * 64];       // 8KB  (single buffer)
    __shared__ short Vts[64][LDP];      // 9KB
    __shared__ short Ps[4][16 * LDP];   // 9KB  -> 26KB total, 4 blocks/CU (grid-capped)

    const int tid = threadIdx.x;
    const int lane = tid & 63;
    const int w = tid >> 6;
    const int lo = lane & 15, hi = lane >> 4;
    const int sx = lo & 7;
    const int lin = blockIdx.x;
    const int bh = lin & 31;
    const int qt = 31 - (lin >> 5);     // LPT: heavy blocks first
    const int b_ = bh >> 4, h = bh & 15;
    const size_t base = (size_t)bh * 2048 * 64;

    const int krow = tid >> 2;
    const int cq = (tid & 3) * 2;
    const int ksw = krow & 7;

    bf16x8 q0, q1;
    {
        const short* src = Q + base + (size_t)(qt * 64 + krow) * 64 + cq * 8;
        bf16x8 a = *reinterpret_cast<const bf16x8*>(src);
        bf16x8 b = *reinterpret_cast<const bf16x8*>(src + 8);
        *reinterpret_cast<bf16x8*>(&Ks[krow * 64 + ((cq ^ ksw) << 3)]) = a;
        *reinterpret_cast<bf16x8*>(&Ks[krow * 64 + (((cq + 1) ^ ksw) << 3)]) = b;
        __syncthreads();
        q0 = *reinterpret_cast<const bf16x8*>(&Ks[(w * 16 + lo) * 64 + ((hi ^ sx) << 3)]);
        q1 = *reinterpret_cast<const bf16x8*>(&Ks[(w * 16 + lo) * 64 + (((4 + hi) ^ sx) << 3)]);
        __syncthreads();
    }

    float m_r = -1e30f, l_r = 0.f;
    f32x4 o_acc[4];
#pragma unroll
    for (int db = 0; db < 4; db++) o_acc[db] = {0.f, 0.f, 0.f, 0.f};

    const int u2 = tid >> 3;
    const int vdb8 = (tid & 7) * 8;
    const int vswz = (tid & 7) << 3;
    const int tw = (2 * u2) ^ vswz;

    // register prefetch of tile j=0
    bf16x8 kr0, kr1, vr0, vr1;
    kr0 = *reinterpret_cast<const bf16x8*>(K + base + (size_t)krow * 64 + cq * 8);
    kr1 = *reinterpret_cast<const bf16x8*>(K + base + (size_t)krow * 64 + cq * 8 + 8);
    vr0 = *reinterpret_cast<const bf16x8*>(V + base + (size_t)(2 * u2) * 64 + vdb8);
    vr1 = *reinterpret_cast<const bf16x8*>(V + base + (size_t)(2 * u2 + 1) * 64 + vdb8);

    for (int j = 0; j <= qt; j++) {
        // write tile j (regs -> single LDS buffer)
        *reinterpret_cast<bf16x8*>(&Ks[krow * 64 + ((cq ^ ksw) << 3)]) = kr0;
        *reinterpret_cast<bf16x8*>(&Ks[krow * 64 + (((cq + 1) ^ ksw) << 3)]) = kr1;
#pragma unroll
        for (int i = 0; i < 8; i++) {
            unsigned int pv = (unsigned int)(unsigned short)vr0[i] |
                              ((unsigned int)(unsigned short)vr1[i] << 16);
            *reinterpret_cast<unsigned int*>(&Vts[vdb8 + i][tw]) = pv;
        }
        __syncthreads();     // writes visible to all waves
        if (j < qt) {        // prefetch tile j+1 (flies under compute)
            const size_t jb2 = (size_t)(j + 1) * 64;
            kr0 = *reinterpret_cast<const bf16x8*>(K + base + (jb2 + krow) * 64 + cq * 8);
            kr1 = *reinterpret_cast<const bf16x8*>(K + base + (jb2 + krow) * 64 + cq * 8 + 8);
            vr0 = *reinterpret_cast<const bf16x8*>(V + base + (jb2 + 2 * u2) * 64 + vdb8);
            vr1 = *reinterpret_cast<const bf16x8*>(V + base + (jb2 + 2 * u2 + 1) * 64 + vdb8);
        }

        attn_tile_compute(q0, q1, Ks, Vts, &Ps[w][0], lane, w, j == qt, m_r, l_r, o_acc);
        __syncthreads();     // all reads done before next iter overwrites buffer
    }

    float inv[4];
#pragma unroll
    for (int r = 0; r < 4; r++) inv[r] = 1.f / __shfl(l_r, (hi << 2) + r, 64);

    short* Op = O + ((size_t)b_ * 2048) * 1024 + (size_t)h * 64;
#pragma unroll
    for (int r = 0; r < 4; r++) {
        const int row = qt * 64 + w * 16 + (hi << 2) + r;
#pragma unroll
        for (int db = 0; db < 4; db++)
            Op[(size_t)row * 1024 + db * 16 + lo] = f2bf(o_acc[db][r] * inv[r]);
    }
}

// ---------------- Out GEMM, 128x128, T2 chunk-swizzle, loose-wave dbuf ---------------
__global__ __launch_bounds__(256) void gemm_out(
    const short* __restrict__ A, const short* __restrict__ W,
    float* __restrict__ C) {
    __shared__ short As[2][128 * 64];
    __shared__ short Bs[2][128 * 64];
    const int tid = threadIdx.x;
    const int lane = tid & 63;
    const int w = tid >> 6;
    const int lo = lane & 15, hi = lane >> 4;
    const int wr = w >> 1, wc = w & 1;
    const int lin = blockIdx.x;
    const int wg = (lin & 7) * 32 + (lin >> 3);
    const int n0 = (wg & 7) * 128;
    const int m0 = (wg >> 3) * 128;
    const int K = 1024;

    f32x4 acc[4][4];
#pragma unroll
    for (int i = 0; i < 4; i++)
#pragma unroll
        for (int j = 0; j < 4; j++) acc[i][j] = {0.f, 0.f, 0.f, 0.f};

    const int srow = w * 8 + (lane >> 3);
    const int scx = (((lane & 7) ^ ((lane >> 3) & 7)) << 3);
    const short* gA = A + (size_t)(m0 + srow) * K + scx;
    const short* gB = W + (size_t)(n0 + srow) * K + scx;

#pragma unroll
    for (int it = 0; it < 4; it++)
        GLDS(gA + (size_t)it * 32 * K, (char*)As[0] + it * 4096 + w * 1024);
#pragma unroll
    for (int it = 0; it < 4; it++)
        GLDS(gB + (size_t)it * 32 * K, (char*)Bs[0] + it * 4096 + w * 1024);

    for (int t = 0; t < 16; t++) {
        const int c = t & 1;
        if (t < 15) {
            const int k1 = (t + 1) * 64;
#pragma unroll
            for (int it = 0; it < 4; it++)
                GLDS(gA + k1 + (size_t)it * 32 * K, (char*)As[c ^ 1] + it * 4096 + w * 1024);
#pragma unroll
            for (int it = 0; it < 4; it++)
                GLDS(gB + k1 + (size_t)it * 32 * K, (char*)Bs[c ^ 1] + it * 4096 + w * 1024);
            VMC8();
        } else {
            VMC0();
        }
        BARSB();
#pragma unroll
        for (int kk = 0; kk < 2; kk++) {
            bf16x8 a[4], b[4];
#pragma unroll
            for (int mi = 0; mi < 4; mi++)
                a[mi] = *reinterpret_cast<const bf16x8*>(
                    &As[c][(wr * 64 + mi * 16 + lo) * 64 + (((kk * 4 + hi) ^ (lo & 7)) << 3)]);
#pragma unroll
            for (int ni = 0; ni < 4; ni++)
                b[ni] = *reinterpret_cast<const bf16x8*>(
                    &Bs[c][(wc * 64 + ni * 16 + lo) * 64 + (((kk * 4 + hi) ^ (lo & 7)) << 3)]);
#pragma unroll
            for (int mi = 0; mi < 4; mi++)
#pragma unroll
                for (int ni = 0; ni < 4; ni++)
                    acc[mi][ni] = __builtin_amdgcn_mfma_f32_16x16x32_bf16(
                        a[mi], b[ni], acc[mi][ni], 0, 0, 0);
        }
        if (t < 15) BARSB();
    }

#pragma unroll
    for (int mi = 0; mi < 4; mi++) {
#pragma unroll
        for (int r = 0; r < 4; r++) {
            const int m = m0 + wr * 64 + mi * 16 + (hi << 2) + r;
#pragma unroll
            for (int ni = 0; ni < 4; ni++) {
                const int n = n0 + wc * 64 + ni * 16 + lo;
                C[(size_t)m * 1024 + n] = acc[mi][ni][r];
            }
        }
    }
}

extern "C" void kernel_launch(void* const* d_in, const int* in_sizes, int n_in,
                              void* d_out, int out_size, void* d_ws, size_t ws_size,
                              hipStream_t stream) {
    const float* x = (const float*)d_in[0];
    const float* wQKV = (const float*)d_in[1];
    const float* wOut = (const float*)d_in[2];
    const float* cosT = (const float*)d_in[3];
    const float* sinT = (const float*)d_in[4];
    float* out = (float*)d_out;

    char* ws = (char*)d_ws;
    const size_t MB = 1024 * 1024;
    short* xb    = (short*)(ws);             // 8MB
    short* wqkvb = (short*)(ws + 8 * MB);    // 6MB
    short* woutb = (short*)(ws + 14 * MB);   // 2MB
    short* Qbuf  = (short*)(ws + 16 * MB);   // 8MB
    short* Kbuf  = (short*)(ws + 24 * MB);   // 8MB
    short* Vbuf  = (short*)(ws + 32 * MB);   // 8MB
    short* Obuf  = (short*)(ws + 40 * MB);   // 8MB (attn out, bf16)
    float2* csT  = (float2*)(ws + 48 * MB);  // 512KB cos/sin table [32][2048]

    cvt_fused<<<8448, 256, 0, stream>>>(x, wQKV, wOut, cosT, sinT, xb, wqkvb, woutb, csT);
    gemm_qkv_rope<<<256, 512, 0, stream>>>(xb, wqkvb, csT, Qbuf, Kbuf, Vbuf);
    attn_kernel<<<1024, 256, 0, stream>>>(Qbuf, Kbuf, Vbuf, Obuf);
    gemm_out<<<256, 256, 0, stream>>>(Obuf, woutb, out);
}

// Round 23
// 107.950 us; speedup vs baseline: 1.0157x; 1.0157x over previous
//
#include <hip/hip_runtime.h>
#include <hip/hip_bf16.h>

typedef __attribute__((ext_vector_type(8))) short bf16x8;
typedef __attribute__((ext_vector_type(4))) short s16x4;
typedef __attribute__((ext_vector_type(4))) float f32x4;

__device__ __forceinline__ short f2bf(float f) {
    unsigned int u = __builtin_bit_cast(unsigned int, f);
    u += 0x7fffu + ((u >> 16) & 1u);
    return (short)(u >> 16);
}

#define GLDS(g, l) __builtin_amdgcn_global_load_lds( \
    (__attribute__((address_space(1))) void*)(g),    \
    (__attribute__((address_space(3))) void*)(l), 16, 0, 0)

#define BARSB() { __builtin_amdgcn_s_barrier(); __builtin_amdgcn_sched_barrier(0); }
#define VMC8()  { asm volatile("s_waitcnt vmcnt(8)" ::: "memory"); __builtin_amdgcn_sched_barrier(0); }
#define VMC7()  { asm volatile("s_waitcnt vmcnt(7)" ::: "memory"); __builtin_amdgcn_sched_barrier(0); }
#define VMC0()  { asm volatile("s_waitcnt vmcnt(0)" ::: "memory"); __builtin_amdgcn_sched_barrier(0); }

// ------ fused fp32->bf16 convert (x, wQKV, wOut) + cos/sin float2 table build --------
__global__ __launch_bounds__(256) void cvt_fused(const float* __restrict__ x,
                                                 const float* __restrict__ wq,
                                                 const float* __restrict__ wo,
                                                 const float* __restrict__ cosT,
                                                 const float* __restrict__ sinT,
                                                 short* __restrict__ xb,
                                                 short* __restrict__ wqb,
                                                 short* __restrict__ wob,
                                                 float2* __restrict__ csT) {
    const int b = blockIdx.x;
    if (b >= 8192) {
        const int idx = (b - 8192) * 256 + threadIdx.x;   // 0..65535
        const int i2 = idx >> 11;
        const int s = idx & 2047;
        csT[idx] = make_float2(cosT[s * 32 + i2], sinT[s * 32 + i2]);
        return;
    }
    const float* in; short* out; int i;
    if (b < 4096)      { in = x;  out = xb;  i = b * 256 + threadIdx.x; }
    else if (b < 7168) { in = wq; out = wqb; i = (b - 4096) * 256 + threadIdx.x; }
    else               { in = wo; out = wob; i = (b - 7168) * 256 + threadIdx.x; }
    float4 v = reinterpret_cast<const float4*>(in)[i];
    s16x4 r = { f2bf(v.x), f2bf(v.y), f2bf(v.z), f2bf(v.w) };
    reinterpret_cast<s16x4*>(out)[i] = r;
}

#define LDP 72

// ---------------- QKV GEMM (+RoPE), 256x192, loose-wave VMC7 ---------
__device__ __forceinline__ void load_a(const short* __restrict__ A, int wr, int lo, int hi,
                                       int mh, bf16x8 aF[4][2]) {
#pragma unroll
    for (int mi = 0; mi < 4; ++mi)
#pragma unroll
        for (int kk = 0; kk < 2; ++kk)
            aF[mi][kk] = *reinterpret_cast<const bf16x8*>(
                &A[(wr * 128 + mh * 64 + mi * 16 + lo) * 64 + (((kk * 4 + hi) ^ (lo & 7)) << 3)]);
}
__device__ __forceinline__ void load_b3(const short* __restrict__ B, int wc, int lo, int hi,
                                        bf16x8 bF[3][2]) {
#pragma unroll
    for (int ni = 0; ni < 3; ++ni)
#pragma unroll
        for (int kk = 0; kk < 2; ++kk)
            bF[ni][kk] = *reinterpret_cast<const bf16x8*>(
                &B[(wc * 48 + ni * 16 + lo) * 64 + (((kk * 4 + hi) ^ (lo & 7)) << 3)]);
}
__device__ __forceinline__ void mfma24(const bf16x8 aF[4][2], const bf16x8 bF[3][2],
                                       f32x4 acc[8][3], int mh) {
#pragma unroll
    for (int mi = 0; mi < 4; ++mi)
#pragma unroll
        for (int ni = 0; ni < 3; ++ni)
#pragma unroll
            for (int kk = 0; kk < 2; ++kk)
                acc[mh * 4 + mi][ni] = __builtin_amdgcn_mfma_f32_16x16x32_bf16(
                    aF[mi][kk], bF[ni][kk], acc[mh * 4 + mi][ni], 0, 0, 0);
}

__global__ __launch_bounds__(512, 1) void gemm_qkv_rope(
    const short* __restrict__ X, const short* __restrict__ W,
    const float2* __restrict__ csT,
    short* __restrict__ Qo, short* __restrict__ Ko, short* __restrict__ Vo) {
    __shared__ short ldsA[2][16384];
    __shared__ short ldsB[2][12288];
    const int tid = threadIdx.x;
    const int lane = tid & 63;
    const int w = tid >> 6;
    const int lo = lane & 15, hi = lane >> 4;
    const int wr = w >> 2, wc = w & 3;
    const int lin = blockIdx.x;
    const int xcd = lin & 7;
    const int i_ = lin >> 3;
    const int m0 = ((xcd >> 1) * 4 + (i_ & 3)) * 256;
    const int n0 = ((xcd & 1) * 8 + (i_ >> 2)) * 192;

    f32x4 acc[8][3];
#pragma unroll
    for (int i = 0; i < 8; i++)
#pragma unroll
        for (int j = 0; j < 3; j++) acc[i][j] = {0.f, 0.f, 0.f, 0.f};

    const int srow8 = w * 8 + (lane >> 3);
    const int scx = (((lane & 7) ^ ((lane >> 3) & 7)) << 3);

#define STAGE_A(BUF, KT, IT) GLDS(X + (size_t)(m0 + (IT) * 64 + srow8) * 1024 + ((KT) << 6) + scx, \
                                  (char*)&ldsA[BUF][0] + (IT) * 8192 + w * 1024)
#define STAGE_B(BUF, KT, IT) GLDS(W + (size_t)(n0 + (IT) * 64 + srow8) * 1024 + ((KT) << 6) + scx, \
                                  (char*)&ldsB[BUF][0] + (IT) * 8192 + w * 1024)

    bf16x8 aF[4][2], bF[3][2];

    STAGE_B(0, 0, 0); STAGE_B(0, 0, 1); STAGE_B(0, 0, 2);
    STAGE_A(0, 0, 0); STAGE_A(0, 0, 1); STAGE_A(0, 0, 2); STAGE_A(0, 0, 3);

    for (int t = 0; t < 16; ++t) {
        const int c = t & 1;
        if (t < 15) {
            const int nb_ = c ^ 1, t1 = t + 1;
            STAGE_B(nb_, t1, 0); STAGE_B(nb_, t1, 1); STAGE_B(nb_, t1, 2);
            STAGE_A(nb_, t1, 0); STAGE_A(nb_, t1, 1); STAGE_A(nb_, t1, 2); STAGE_A(nb_, t1, 3);
            VMC7();
        } else {
            VMC0();
        }
        BARSB();
        load_a(&ldsA[c][0], wr, lo, hi, 0, aF);
        load_b3(&ldsB[c][0], wc, lo, hi, bF);
        mfma24(aF, bF, acc, 0);
        load_a(&ldsA[c][0], wr, lo, hi, 1, aF);
        mfma24(aF, bF, acc, 1);
        if (t < 15) BARSB();
    }
#undef STAGE_A
#undef STAGE_B

    // ---- RoPE epilogue with coalesced float2 cos/sin table ----
    const int sfull = m0 + wr * 128 + (hi << 2);
    const int b_ = sfull >> 11;
    const int srow_ = sfull & 2047;
#pragma unroll
    for (int ni = 0; ni < 3; ni++) {
        const int n = n0 + wc * 48 + ni * 16 + lo;
        const int region = n >> 10;
        const int c = n & 1023;
        const int h = c >> 6;
        const int d = c & 63;
        const size_t obase = ((size_t)(b_ * 16 + h) * 2048 + srow_) * 64 + d;
        if (region == 2) {
#pragma unroll
            for (int mi = 0; mi < 8; mi++)
#pragma unroll
                for (int r = 0; r < 4; r++)
                    Vo[obase + (size_t)(mi * 16 + r) * 64] = f2bf(acc[mi][ni][r]);
        } else {
            short* dst = (region == 0) ? Qo : Ko;
            const float scale = (region == 0) ? 0.18033688f : 1.0f;  // 1/8 * log2(e)
            const float2* csrow = csT + (size_t)(d >> 1) * 2048 + srow_;
#pragma unroll
            for (int mi = 0; mi < 8; mi++) {
                float4 t0 = *reinterpret_cast<const float4*>(csrow + mi * 16);
                float4 t1 = *reinterpret_cast<const float4*>(csrow + mi * 16 + 2);
                const float cs_[4] = {t0.x, t0.z, t1.x, t1.z};
                const float sn_[4] = {t0.y, t0.w, t1.y, t1.w};
#pragma unroll
                for (int r = 0; r < 4; r++) {
                    float v = acc[mi][ni][r];
                    float other = __shfl_xor(v, 1, 64);
                    float outv = (d & 1) ? (v * cs_[r] + other * sn_[r])
                                         : (v * cs_[r] - other * sn_[r]);
                    dst[obase + (size_t)(mi * 16 + r) * 64] = f2bf(outv * scale);
                }
            }
        }
    }
}

// ---------------- Flash attention (exp2 softmax, defer-max, cvt_pk, swizzled K) ------
__device__ __forceinline__ void attn_tile_compute(
    const bf16x8 q0, const bf16x8 q1,
    const short* __restrict__ Ks,          // [64*64] chunk-XOR swizzled
    const short (*Vts)[LDP], short* __restrict__ Pw,
    const int lane, const int w, const bool diag,
    float& m_r, float& l_r, f32x4* __restrict__ o_acc) {
    const int lo = lane & 15, hi = lane >> 4;
    const int sx = lo & 7;

    f32x4 sc[4];
#pragma unroll
    for (int nb = 0; nb < 4; nb++) sc[nb] = {0.f, 0.f, 0.f, 0.f};
#pragma unroll
    for (int nb = 0; nb < 4; nb++) {
        const short* kr = &Ks[(nb * 16 + lo) * 64];
        bf16x8 k0 = *reinterpret_cast<const bf16x8*>(&kr[(hi ^ sx) << 3]);
        sc[nb] = __builtin_amdgcn_mfma_f32_16x16x32_bf16(k0, q0, sc[nb], 0, 0, 0);
        bf16x8 k1 = *reinterpret_cast<const bf16x8*>(&kr[((4 + hi) ^ sx) << 3]);
        sc[nb] = __builtin_amdgcn_mfma_f32_16x16x32_bf16(k1, q1, sc[nb], 0, 0, 0);
    }
    if (diag) {
        const int q_ = w * 16 + lo;
        const int kb = (hi << 2);
#pragma unroll
        for (int nb = 0; nb < 4; nb++) {
            const int k_ = nb * 16 + kb;
#pragma unroll
            for (int r = 0; r < 4; r++)
                if (k_ + r > q_) sc[nb][r] = -1e30f;
        }
    }

    float mx = sc[0][0];
#pragma unroll
    for (int nb = 0; nb < 4; nb++)
#pragma unroll
        for (int r = 0; r < 4; r++) mx = fmaxf(mx, sc[nb][r]);
    mx = fmaxf(mx, __shfl_xor(mx, 16, 64));
    mx = fmaxf(mx, __shfl_xor(mx, 32, 64));

    if (!__all(mx <= m_r + 8.0f)) {
        const float mnew = fmaxf(m_r, mx);
        const float alpha = __builtin_amdgcn_exp2f(m_r - mnew);
        m_r = mnew;
        l_r *= alpha;
        float aq[4];
#pragma unroll
        for (int r = 0; r < 4; r++) aq[r] = __shfl(alpha, (hi << 2) + r, 64);
#pragma unroll
        for (int db = 0; db < 4; db++)
#pragma unroll
            for (int r = 0; r < 4; r++) o_acc[db][r] *= aq[r];
    }

    float rs = 0.f;
#pragma unroll
    for (int nb = 0; nb < 4; nb++)
#pragma unroll
        for (int r = 0; r < 4; r++) {
            float e = __builtin_amdgcn_exp2f(sc[nb][r] - m_r);
            sc[nb][r] = e;
            rs += e;
        }
    rs += __shfl_xor(rs, 16, 64);
    rs += __shfl_xor(rs, 32, 64);
    l_r += rs;

    unsigned int* Pw32 = reinterpret_cast<unsigned int*>(Pw);
#pragma unroll
    for (int nb = 0; nb < 4; nb++)
#pragma unroll
        for (int rr = 0; rr < 2; rr++) {
            unsigned int pk;
            asm("v_cvt_pk_bf16_f32 %0, %1, %2"
                : "=v"(pk) : "v"(sc[nb][2 * rr]), "v"(sc[nb][2 * rr + 1]));
            Pw32[lo * (LDP / 2) + nb * 8 + (hi << 1) + rr] = pk;
        }

#pragma unroll
    for (int kk = 0; kk < 2; kk++) {
        bf16x8 pa = *reinterpret_cast<const bf16x8*>(&Pw[lo * LDP + kk * 32 + hi * 8]);
#pragma unroll
        for (int db = 0; db < 4; db++) {
            const int d = db * 16 + lo;
            const int tsw = (kk * 32 + hi * 8) ^ ((((d >> 3) & 7)) << 3);
            bf16x8 vb = *reinterpret_cast<const bf16x8*>(&Vts[d][tsw]);
            o_acc[db] = __builtin_amdgcn_mfma_f32_16x16x32_bf16(pa, vb, o_acc[db], 0, 0, 0);
        }
    }
}

__global__ __launch_bounds__(256) void attn_kernel(
    const short* __restrict__ Q, const short* __restrict__ K,
    const short* __restrict__ V, short* __restrict__ O) {
    __shared__ short Ks[2][64 * 64];
    __shared__ short Vts[2][64][LDP];
    __shared__ short Ps[4][16 * LDP];

    const int tid = threadIdx.x;
    const int lane = tid & 63;
    const int w = tid >> 6;
    const int lo = lane & 15, hi = lane >> 4;
    const int sx = lo & 7;
    const int lin = blockIdx.x;
    const int bh = lin & 31;
    const int qt = 31 - (lin >> 5);     // LPT: heavy blocks first
    const int b_ = bh >> 4, h = bh & 15;
    const size_t base = (size_t)bh * 2048 * 64;

    const int krow = tid >> 2;
    const int cq = (tid & 3) * 2;
    const int ksw = krow & 7;

    bf16x8 q0, q1;
    {
        const short* src = Q + base + (size_t)(qt * 64 + krow) * 64 + cq * 8;
        bf16x8 a = *reinterpret_cast<const bf16x8*>(src);
        bf16x8 b = *reinterpret_cast<const bf16x8*>(src + 8);
        *reinterpret_cast<bf16x8*>(&Ks[0][krow * 64 + ((cq ^ ksw) << 3)]) = a;
        *reinterpret_cast<bf16x8*>(&Ks[0][krow * 64 + (((cq + 1) ^ ksw) << 3)]) = b;
        __syncthreads();
        q0 = *reinterpret_cast<const bf16x8*>(&Ks[0][(w * 16 + lo) * 64 + ((hi ^ sx) << 3)]);
        q1 = *reinterpret_cast<const bf16x8*>(&Ks[0][(w * 16 + lo) * 64 + (((4 + hi) ^ sx) << 3)]);
        __syncthreads();
    }

    float m_r = -1e30f, l_r = 0.f;
    f32x4 o_acc[4];
#pragma unroll
    for (int db = 0; db < 4; db++) o_acc[db] = {0.f, 0.f, 0.f, 0.f};

    const int u2 = tid >> 3;
    const int vdb8 = (tid & 7) * 8;
    const int vswz = (tid & 7) << 3;
    const int tw = (2 * u2) ^ vswz;

    bf16x8 kr0, kr1, vr0, vr1;
    kr0 = *reinterpret_cast<const bf16x8*>(K + base + (size_t)krow * 64 + cq * 8);
    kr1 = *reinterpret_cast<const bf16x8*>(K + base + (size_t)krow * 64 + cq * 8 + 8);
    vr0 = *reinterpret_cast<const bf16x8*>(V + base + (size_t)(2 * u2) * 64 + vdb8);
    vr1 = *reinterpret_cast<const bf16x8*>(V + base + (size_t)(2 * u2 + 1) * 64 + vdb8);

    int c = 0;
    for (int j = 0; j <= qt; j++) {
        *reinterpret_cast<bf16x8*>(&Ks[c][krow * 64 + ((cq ^ ksw) << 3)]) = kr0;
        *reinterpret_cast<bf16x8*>(&Ks[c][krow * 64 + (((cq + 1) ^ ksw) << 3)]) = kr1;
#pragma unroll
        for (int i = 0; i < 8; i++) {
            unsigned int pv = (unsigned int)(unsigned short)vr0[i] |
                              ((unsigned int)(unsigned short)vr1[i] << 16);
            *reinterpret_cast<unsigned int*>(&Vts[c][vdb8 + i][tw]) = pv;
        }
        __syncthreads();
        if (j < qt) {
            const size_t jb2 = (size_t)(j + 1) * 64;
            kr0 = *reinterpret_cast<const bf16x8*>(K + base + (jb2 + krow) * 64 + cq * 8);
            kr1 = *reinterpret_cast<const bf16x8*>(K + base + (jb2 + krow) * 64 + cq * 8 + 8);
            vr0 = *reinterpret_cast<const bf16x8*>(V + base + (jb2 + 2 * u2) * 64 + vdb8);
            vr1 = *reinterpret_cast<const bf16x8*>(V + base + (jb2 + 2 * u2 + 1) * 64 + vdb8);
        }

        attn_tile_compute(q0, q1, Ks[c], Vts[c], &Ps[w][0], lane, w, j == qt, m_r, l_r, o_acc);
        c ^= 1;
    }

    float inv[4];
#pragma unroll
    for (int r = 0; r < 4; r++) inv[r] = 1.f / __shfl(l_r, (hi << 2) + r, 64);

    short* Op = O + ((size_t)b_ * 2048) * 1024 + (size_t)h * 64;
#pragma unroll
    for (int r = 0; r < 4; r++) {
        const int row = qt * 64 + w * 16 + (hi << 2) + r;
#pragma unroll
        for (int db = 0; db < 4; db++)
            Op[(size_t)row * 1024 + db * 16 + lo] = f2bf(o_acc[db][r] * inv[r]);
    }
}

// ---------------- Out GEMM, 128x128, T2 chunk-swizzle, loose-wave dbuf ---------------
__global__ __launch_bounds__(256) void gemm_out(
    const short* __restrict__ A, const short* __restrict__ W,
    float* __restrict__ C) {
    __shared__ short As[2][128 * 64];
    __shared__ short Bs[2][128 * 64];
    const int tid = threadIdx.x;
    const int lane = tid & 63;
    const int w = tid >> 6;
    const int lo = lane & 15, hi = lane >> 4;
    const int wr = w >> 1, wc = w & 1;
    const int lin = blockIdx.x;
    const int wg = (lin & 7) * 32 + (lin >> 3);
    const int n0 = (wg & 7) * 128;
    const int m0 = (wg >> 3) * 128;
    const int K = 1024;

    f32x4 acc[4][4];
#pragma unroll
    for (int i = 0; i < 4; i++)
#pragma unroll
        for (int j = 0; j < 4; j++) acc[i][j] = {0.f, 0.f, 0.f, 0.f};

    const int srow = w * 8 + (lane >> 3);
    const int scx = (((lane & 7) ^ ((lane >> 3) & 7)) << 3);
    const short* gA = A + (size_t)(m0 + srow) * K + scx;
    const short* gB = W + (size_t)(n0 + srow) * K + scx;

#pragma unroll
    for (int it = 0; it < 4; it++)
        GLDS(gA + (size_t)it * 32 * K, (char*)As[0] + it * 4096 + w * 1024);
#pragma unroll
    for (int it = 0; it < 4; it++)
        GLDS(gB + (size_t)it * 32 * K, (char*)Bs[0] + it * 4096 + w * 1024);

    for (int t = 0; t < 16; t++) {
        const int c = t & 1;
        if (t < 15) {
            const int k1 = (t + 1) * 64;
#pragma unroll
            for (int it = 0; it < 4; it++)
                GLDS(gA + k1 + (size_t)it * 32 * K, (char*)As[c ^ 1] + it * 4096 + w * 1024);
#pragma unroll
            for (int it = 0; it < 4; it++)
                GLDS(gB + k1 + (size_t)it * 32 * K, (char*)Bs[c ^ 1] + it * 4096 + w * 1024);
            VMC8();
        } else {
            VMC0();
        }
        BARSB();
#pragma unroll
        for (int kk = 0; kk < 2; kk++) {
            bf16x8 a[4], b[4];
#pragma unroll
            for (int mi = 0; mi < 4; mi++)
                a[mi] = *reinterpret_cast<const bf16x8*>(
                    &As[c][(wr * 64 + mi * 16 + lo) * 64 + (((kk * 4 + hi) ^ (lo & 7)) << 3)]);
#pragma unroll
            for (int ni = 0; ni < 4; ni++)
                b[ni] = *reinterpret_cast<const bf16x8*>(
                    &Bs[c][(wc * 64 + ni * 16 + lo) * 64 + (((kk * 4 + hi) ^ (lo & 7)) << 3)]);
#pragma unroll
            for (int mi = 0; mi < 4; mi++)
#pragma unroll
                for (int ni = 0; ni < 4; ni++)
                    acc[mi][ni] = __builtin_amdgcn_mfma_f32_16x16x32_bf16(
                        a[mi], b[ni], acc[mi][ni], 0, 0, 0);
        }
        if (t < 15) BARSB();
    }

#pragma unroll
    for (int mi = 0; mi < 4; mi++) {
#pragma unroll
        for (int r = 0; r < 4; r++) {
            const int m = m0 + wr * 64 + mi * 16 + (hi << 2) + r;
#pragma unroll
            for (int ni = 0; ni < 4; ni++) {
                const int n = n0 + wc * 64 + ni * 16 + lo;
                C[(size_t)m * 1024 + n] = acc[mi][ni][r];
            }
        }
    }
}

extern "C" void kernel_launch(void* const* d_in, const int* in_sizes, int n_in,
                              void* d_out, int out_size, void* d_ws, size_t ws_size,
                              hipStream_t stream) {
    const float* x = (const float*)d_in[0];
    const float* wQKV = (const float*)d_in[1];
    const float* wOut = (const float*)d_in[2];
    const float* cosT = (const float*)d_in[3];
    const float* sinT = (const float*)d_in[4];
    float* out = (float*)d_out;

    char* ws = (char*)d_ws;
    const size_t MB = 1024 * 1024;
    short* xb    = (short*)(ws);             // 8MB
    short* wqkvb = (short*)(ws + 8 * MB);    // 6MB
    short* woutb = (short*)(ws + 14 * MB);   // 2MB
    short* Qbuf  = (short*)(ws + 16 * MB);   // 8MB
    short* Kbuf  = (short*)(ws + 24 * MB);   // 8MB
    short* Vbuf  = (short*)(ws + 32 * MB);   // 8MB
    short* Obuf  = (short*)(ws + 40 * MB);   // 8MB (attn out, bf16)
    float2* csT  = (float2*)(ws + 48 * MB);  // 512KB cos/sin table [32][2048]

    cvt_fused<<<8448, 256, 0, stream>>>(x, wQKV, wOut, cosT, sinT, xb, wqkvb, woutb, csT);
    gemm_qkv_rope<<<256, 512, 0, stream>>>(xb, wqkvb, csT, Qbuf, Kbuf, Vbuf);
    attn_kernel<<<1024, 256, 0, stream>>>(Qbuf, Kbuf, Vbuf, Obuf);
    gemm_out<<<256, 256, 0, stream>>>(Obuf, woutb, out);
}

// Round 24
// 106.743 us; speedup vs baseline: 1.0271x; 1.0113x over previous
//
#include <hip/hip_runtime.h>
#include <hip/hip_bf16.h>

typedef __attribute__((ext_vector_type(8))) short bf16x8;
typedef __attribute__((ext_vector_type(4))) short s16x4;
typedef __attribute__((ext_vector_type(4))) float f32x4;

__device__ __forceinline__ short f2bf(float f) {
    unsigned int u = __builtin_bit_cast(unsigned int, f);
    u += 0x7fffu + ((u >> 16) & 1u);
    return (short)(u >> 16);
}

#define GLDS(g, l) __builtin_amdgcn_global_load_lds( \
    (__attribute__((address_space(1))) void*)(g),    \
    (__attribute__((address_space(3))) void*)(l), 16, 0, 0)

#define BARSB() { __builtin_amdgcn_s_barrier(); __builtin_amdgcn_sched_barrier(0); }
#define VMC8()  { asm volatile("s_waitcnt vmcnt(8)" ::: "memory"); __builtin_amdgcn_sched_barrier(0); }
#define VMC7()  { asm volatile("s_waitcnt vmcnt(7)" ::: "memory"); __builtin_amdgcn_sched_barrier(0); }
#define VMC0()  { asm volatile("s_waitcnt vmcnt(0)" ::: "memory"); __builtin_amdgcn_sched_barrier(0); }

// ------ fused fp32->bf16 convert (x, wQKV, wOut) + cos/sin float2 table build --------
__global__ __launch_bounds__(256) void cvt_fused(const float* __restrict__ x,
                                                 const float* __restrict__ wq,
                                                 const float* __restrict__ wo,
                                                 const float* __restrict__ cosT,
                                                 const float* __restrict__ sinT,
                                                 short* __restrict__ xb,
                                                 short* __restrict__ wqb,
                                                 short* __restrict__ wob,
                                                 float2* __restrict__ csT) {
    const int b = blockIdx.x;
    if (b >= 8192) {
        const int idx = (b - 8192) * 256 + threadIdx.x;   // 0..65535
        const int i2 = idx >> 11;
        const int s = idx & 2047;
        csT[idx] = make_float2(cosT[s * 32 + i2], sinT[s * 32 + i2]);
        return;
    }
    const float* in; short* out; int i;
    if (b < 4096)      { in = x;  out = xb;  i = b * 256 + threadIdx.x; }
    else if (b < 7168) { in = wq; out = wqb; i = (b - 4096) * 256 + threadIdx.x; }
    else               { in = wo; out = wob; i = (b - 7168) * 256 + threadIdx.x; }
    float4 v = reinterpret_cast<const float4*>(in)[i];
    s16x4 r = { f2bf(v.x), f2bf(v.y), f2bf(v.z), f2bf(v.w) };
    reinterpret_cast<s16x4*>(out)[i] = r;
}

#define LDP 72

// ---------------- QKV GEMM (+RoPE), 256x192, loose-wave VMC7 ---------
__device__ __forceinline__ void load_a(const short* __restrict__ A, int wr, int lo, int hi,
                                       int mh, bf16x8 aF[4][2]) {
#pragma unroll
    for (int mi = 0; mi < 4; ++mi)
#pragma unroll
        for (int kk = 0; kk < 2; ++kk)
            aF[mi][kk] = *reinterpret_cast<const bf16x8*>(
                &A[(wr * 128 + mh * 64 + mi * 16 + lo) * 64 + (((kk * 4 + hi) ^ (lo & 7)) << 3)]);
}
__device__ __forceinline__ void load_b3(const short* __restrict__ B, int wc, int lo, int hi,
                                        bf16x8 bF[3][2]) {
#pragma unroll
    for (int ni = 0; ni < 3; ++ni)
#pragma unroll
        for (int kk = 0; kk < 2; ++kk)
            bF[ni][kk] = *reinterpret_cast<const bf16x8*>(
                &B[(wc * 48 + ni * 16 + lo) * 64 + (((kk * 4 + hi) ^ (lo & 7)) << 3)]);
}
__device__ __forceinline__ void mfma24(const bf16x8 aF[4][2], const bf16x8 bF[3][2],
                                       f32x4 acc[8][3], int mh) {
#pragma unroll
    for (int mi = 0; mi < 4; ++mi)
#pragma unroll
        for (int ni = 0; ni < 3; ++ni)
#pragma unroll
            for (int kk = 0; kk < 2; ++kk)
                acc[mh * 4 + mi][ni] = __builtin_amdgcn_mfma_f32_16x16x32_bf16(
                    aF[mi][kk], bF[ni][kk], acc[mh * 4 + mi][ni], 0, 0, 0);
}

__global__ __launch_bounds__(512, 1) void gemm_qkv_rope(
    const short* __restrict__ X, const short* __restrict__ W,
    const float2* __restrict__ csT,
    short* __restrict__ Qo, short* __restrict__ Ko, short* __restrict__ Vo) {
    __shared__ short ldsA[2][16384];
    __shared__ short ldsB[2][12288];
    const int tid = threadIdx.x;
    const int lane = tid & 63;
    const int w = tid >> 6;
    const int lo = lane & 15, hi = lane >> 4;
    const int wr = w >> 2, wc = w & 3;
    const int lin = blockIdx.x;
    const int xcd = lin & 7;
    const int i_ = lin >> 3;
    const int m0 = ((xcd >> 1) * 4 + (i_ & 3)) * 256;
    const int n0 = ((xcd & 1) * 8 + (i_ >> 2)) * 192;

    f32x4 acc[8][3];
#pragma unroll
    for (int i = 0; i < 8; i++)
#pragma unroll
        for (int j = 0; j < 3; j++) acc[i][j] = {0.f, 0.f, 0.f, 0.f};

    const int srow8 = w * 8 + (lane >> 3);
    const int scx = (((lane & 7) ^ ((lane >> 3) & 7)) << 3);

#define STAGE_A(BUF, KT, IT) GLDS(X + (size_t)(m0 + (IT) * 64 + srow8) * 1024 + ((KT) << 6) + scx, \
                                  (char*)&ldsA[BUF][0] + (IT) * 8192 + w * 1024)
#define STAGE_B(BUF, KT, IT) GLDS(W + (size_t)(n0 + (IT) * 64 + srow8) * 1024 + ((KT) << 6) + scx, \
                                  (char*)&ldsB[BUF][0] + (IT) * 8192 + w * 1024)

    bf16x8 aF[4][2], bF[3][2];

    STAGE_B(0, 0, 0); STAGE_B(0, 0, 1); STAGE_B(0, 0, 2);
    STAGE_A(0, 0, 0); STAGE_A(0, 0, 1); STAGE_A(0, 0, 2); STAGE_A(0, 0, 3);

    for (int t = 0; t < 16; ++t) {
        const int c = t & 1;
        if (t < 15) {
            const int nb_ = c ^ 1, t1 = t + 1;
            STAGE_B(nb_, t1, 0); STAGE_B(nb_, t1, 1); STAGE_B(nb_, t1, 2);
            STAGE_A(nb_, t1, 0); STAGE_A(nb_, t1, 1); STAGE_A(nb_, t1, 2); STAGE_A(nb_, t1, 3);
            VMC7();
        } else {
            VMC0();
        }
        BARSB();
        load_a(&ldsA[c][0], wr, lo, hi, 0, aF);
        load_b3(&ldsB[c][0], wc, lo, hi, bF);
        mfma24(aF, bF, acc, 0);
        load_a(&ldsA[c][0], wr, lo, hi, 1, aF);
        mfma24(aF, bF, acc, 1);
        if (t < 15) BARSB();
    }
#undef STAGE_A
#undef STAGE_B

    // ---- RoPE epilogue with coalesced float2 cos/sin table ----
    const int sfull = m0 + wr * 128 + (hi << 2);
    const int b_ = sfull >> 11;
    const int srow_ = sfull & 2047;
#pragma unroll
    for (int ni = 0; ni < 3; ni++) {
        const int n = n0 + wc * 48 + ni * 16 + lo;
        const int region = n >> 10;
        const int c = n & 1023;
        const int h = c >> 6;
        const int d = c & 63;
        const size_t obase = ((size_t)(b_ * 16 + h) * 2048 + srow_) * 64 + d;
        if (region == 2) {
#pragma unroll
            for (int mi = 0; mi < 8; mi++)
#pragma unroll
                for (int r = 0; r < 4; r++)
                    Vo[obase + (size_t)(mi * 16 + r) * 64] = f2bf(acc[mi][ni][r]);
        } else {
            short* dst = (region == 0) ? Qo : Ko;
            const float scale = (region == 0) ? 0.18033688f : 1.0f;  // 1/8 * log2(e)
            const float2* csrow = csT + (size_t)(d >> 1) * 2048 + srow_;
#pragma unroll
            for (int mi = 0; mi < 8; mi++) {
                float4 t0 = *reinterpret_cast<const float4*>(csrow + mi * 16);
                float4 t1 = *reinterpret_cast<const float4*>(csrow + mi * 16 + 2);
                const float cs_[4] = {t0.x, t0.z, t1.x, t1.z};
                const float sn_[4] = {t0.y, t0.w, t1.y, t1.w};
#pragma unroll
                for (int r = 0; r < 4; r++) {
                    float v = acc[mi][ni][r];
                    float other = __shfl_xor(v, 1, 64);
                    float outv = (d & 1) ? (v * cs_[r] + other * sn_[r])
                                         : (v * cs_[r] - other * sn_[r]);
                    dst[obase + (size_t)(mi * 16 + r) * 64] = f2bf(outv * scale);
                }
            }
        }
    }
}

// ---------------- Flash attention (exp2, defer-max, cvt_pk, deferred l-reduce) -------
// l_r is kept as a PER-LANE partial sum (this lane's k-slices for q-row lo); the
// cross-hi reduction commutes with the online update (alpha depends only on lo) and
// is done ONCE in the epilogue instead of per tile (saves 2 dependent shfl per tile).
__device__ __forceinline__ void attn_tile_compute(
    const bf16x8 q0, const bf16x8 q1,
    const short* __restrict__ Ks,          // [64*64] chunk-XOR swizzled
    const short (*Vts)[LDP], short* __restrict__ Pw,
    const int lane, const int w, const bool diag,
    float& m_r, float& l_r, f32x4* __restrict__ o_acc) {
    const int lo = lane & 15, hi = lane >> 4;
    const int sx = lo & 7;

    f32x4 sc[4];
#pragma unroll
    for (int nb = 0; nb < 4; nb++) sc[nb] = {0.f, 0.f, 0.f, 0.f};
#pragma unroll
    for (int nb = 0; nb < 4; nb++) {
        const short* kr = &Ks[(nb * 16 + lo) * 64];
        bf16x8 k0 = *reinterpret_cast<const bf16x8*>(&kr[(hi ^ sx) << 3]);
        sc[nb] = __builtin_amdgcn_mfma_f32_16x16x32_bf16(k0, q0, sc[nb], 0, 0, 0);
        bf16x8 k1 = *reinterpret_cast<const bf16x8*>(&kr[((4 + hi) ^ sx) << 3]);
        sc[nb] = __builtin_amdgcn_mfma_f32_16x16x32_bf16(k1, q1, sc[nb], 0, 0, 0);
    }
    if (diag) {
        const int q_ = w * 16 + lo;
        const int kb = (hi << 2);
#pragma unroll
        for (int nb = 0; nb < 4; nb++) {
            const int k_ = nb * 16 + kb;
#pragma unroll
            for (int r = 0; r < 4; r++)
                if (k_ + r > q_) sc[nb][r] = -1e30f;
        }
    }

    float mx = sc[0][0];
#pragma unroll
    for (int nb = 0; nb < 4; nb++)
#pragma unroll
        for (int r = 0; r < 4; r++) mx = fmaxf(mx, sc[nb][r]);
    mx = fmaxf(mx, __shfl_xor(mx, 16, 64));
    mx = fmaxf(mx, __shfl_xor(mx, 32, 64));

    if (!__all(mx <= m_r + 8.0f)) {
        const float mnew = fmaxf(m_r, mx);
        const float alpha = __builtin_amdgcn_exp2f(m_r - mnew);   // alpha depends on lo only
        m_r = mnew;
        l_r *= alpha;                                             // per-lane partial: valid
        float aq[4];
#pragma unroll
        for (int r = 0; r < 4; r++) aq[r] = __shfl(alpha, (hi << 2) + r, 64);
#pragma unroll
        for (int db = 0; db < 4; db++)
#pragma unroll
            for (int r = 0; r < 4; r++) o_acc[db][r] *= aq[r];
    }

    float rs = 0.f;
#pragma unroll
    for (int nb = 0; nb < 4; nb++)
#pragma unroll
        for (int r = 0; r < 4; r++) {
            float e = __builtin_amdgcn_exp2f(sc[nb][r] - m_r);
            sc[nb][r] = e;
            rs += e;
        }
    l_r += rs;   // deferred: no cross-lane reduction here

    unsigned int* Pw32 = reinterpret_cast<unsigned int*>(Pw);
#pragma unroll
    for (int nb = 0; nb < 4; nb++)
#pragma unroll
        for (int rr = 0; rr < 2; rr++) {
            unsigned int pk;
            asm("v_cvt_pk_bf16_f32 %0, %1, %2"
                : "=v"(pk) : "v"(sc[nb][2 * rr]), "v"(sc[nb][2 * rr + 1]));
            Pw32[lo * (LDP / 2) + nb * 8 + (hi << 1) + rr] = pk;
        }

#pragma unroll
    for (int kk = 0; kk < 2; kk++) {
        bf16x8 pa = *reinterpret_cast<const bf16x8*>(&Pw[lo * LDP + kk * 32 + hi * 8]);
#pragma unroll
        for (int db = 0; db < 4; db++) {
            const int d = db * 16 + lo;
            const int tsw = (kk * 32 + hi * 8) ^ ((((d >> 3) & 7)) << 3);
            bf16x8 vb = *reinterpret_cast<const bf16x8*>(&Vts[d][tsw]);
            o_acc[db] = __builtin_amdgcn_mfma_f32_16x16x32_bf16(pa, vb, o_acc[db], 0, 0, 0);
        }
    }
}

__global__ __launch_bounds__(256) void attn_kernel(
    const short* __restrict__ Q, const short* __restrict__ K,
    const short* __restrict__ V, short* __restrict__ O) {
    __shared__ short Ks[2][64 * 64];
    __shared__ short Vts[2][64][LDP];
    __shared__ short Ps[4][16 * LDP];

    const int tid = threadIdx.x;
    const int lane = tid & 63;
    const int w = tid >> 6;
    const int lo = lane & 15, hi = lane >> 4;
    const int sx = lo & 7;
    const int lin = blockIdx.x;
    const int bh = lin & 31;
    const int qt = 31 - (lin >> 5);     // LPT: heavy blocks first
    const int b_ = bh >> 4, h = bh & 15;
    const size_t base = (size_t)bh * 2048 * 64;

    const int krow = tid >> 2;
    const int cq = (tid & 3) * 2;
    const int ksw = krow & 7;

    bf16x8 q0, q1;
    {
        const short* src = Q + base + (size_t)(qt * 64 + krow) * 64 + cq * 8;
        bf16x8 a = *reinterpret_cast<const bf16x8*>(src);
        bf16x8 b = *reinterpret_cast<const bf16x8*>(src + 8);
        *reinterpret_cast<bf16x8*>(&Ks[0][krow * 64 + ((cq ^ ksw) << 3)]) = a;
        *reinterpret_cast<bf16x8*>(&Ks[0][krow * 64 + (((cq + 1) ^ ksw) << 3)]) = b;
        __syncthreads();
        q0 = *reinterpret_cast<const bf16x8*>(&Ks[0][(w * 16 + lo) * 64 + ((hi ^ sx) << 3)]);
        q1 = *reinterpret_cast<const bf16x8*>(&Ks[0][(w * 16 + lo) * 64 + (((4 + hi) ^ sx) << 3)]);
        __syncthreads();
    }

    float m_r = -1e30f, l_r = 0.f;
    f32x4 o_acc[4];
#pragma unroll
    for (int db = 0; db < 4; db++) o_acc[db] = {0.f, 0.f, 0.f, 0.f};

    const int u2 = tid >> 3;
    const int vdb8 = (tid & 7) * 8;
    const int vswz = (tid & 7) << 3;
    const int tw = (2 * u2) ^ vswz;

    bf16x8 kr0, kr1, vr0, vr1;
    kr0 = *reinterpret_cast<const bf16x8*>(K + base + (size_t)krow * 64 + cq * 8);
    kr1 = *reinterpret_cast<const bf16x8*>(K + base + (size_t)krow * 64 + cq * 8 + 8);
    vr0 = *reinterpret_cast<const bf16x8*>(V + base + (size_t)(2 * u2) * 64 + vdb8);
    vr1 = *reinterpret_cast<const bf16x8*>(V + base + (size_t)(2 * u2 + 1) * 64 + vdb8);

    int c = 0;
    for (int j = 0; j <= qt; j++) {
        *reinterpret_cast<bf16x8*>(&Ks[c][krow * 64 + ((cq ^ ksw) << 3)]) = kr0;
        *reinterpret_cast<bf16x8*>(&Ks[c][krow * 64 + (((cq + 1) ^ ksw) << 3)]) = kr1;
#pragma unroll
        for (int i = 0; i < 8; i++) {
            unsigned int pv = (unsigned int)(unsigned short)vr0[i] |
                              ((unsigned int)(unsigned short)vr1[i] << 16);
            *reinterpret_cast<unsigned int*>(&Vts[c][vdb8 + i][tw]) = pv;
        }
        __syncthreads();
        if (j < qt) {
            const size_t jb2 = (size_t)(j + 1) * 64;
            kr0 = *reinterpret_cast<const bf16x8*>(K + base + (jb2 + krow) * 64 + cq * 8);
            kr1 = *reinterpret_cast<const bf16x8*>(K + base + (jb2 + krow) * 64 + cq * 8 + 8);
            vr0 = *reinterpret_cast<const bf16x8*>(V + base + (jb2 + 2 * u2) * 64 + vdb8);
            vr1 = *reinterpret_cast<const bf16x8*>(V + base + (jb2 + 2 * u2 + 1) * 64 + vdb8);
        }

        attn_tile_compute(q0, q1, Ks[c], Vts[c], &Ps[w][0], lane, w, j == qt, m_r, l_r, o_acc);
        c ^= 1;
    }

    // finalize deferred l reduction (once per block instead of per tile)
    l_r += __shfl_xor(l_r, 16, 64);
    l_r += __shfl_xor(l_r, 32, 64);

    float inv[4];
#pragma unroll
    for (int r = 0; r < 4; r++) inv[r] = 1.f / __shfl(l_r, (hi << 2) + r, 64);

    short* Op = O + ((size_t)b_ * 2048) * 1024 + (size_t)h * 64;
#pragma unroll
    for (int r = 0; r < 4; r++) {
        const int row = qt * 64 + w * 16 + (hi << 2) + r;
#pragma unroll
        for (int db = 0; db < 4; db++)
            Op[(size_t)row * 1024 + db * 16 + lo] = f2bf(o_acc[db][r] * inv[r]);
    }
}

// ---------------- Out GEMM, 128x128, T2 chunk-swizzle, loose-wave dbuf ---------------
__global__ __launch_bounds__(256) void gemm_out(
    const short* __restrict__ A, const short* __restrict__ W,
    float* __restrict__ C) {
    __shared__ short As[2][128 * 64];
    __shared__ short Bs[2][128 * 64];
    const int tid = threadIdx.x;
    const int lane = tid & 63;
    const int w = tid >> 6;
    const int lo = lane & 15, hi = lane >> 4;
    const int wr = w >> 1, wc = w & 1;
    const int lin = blockIdx.x;
    const int wg = (lin & 7) * 32 + (lin >> 3);
    const int n0 = (wg & 7) * 128;
    const int m0 = (wg >> 3) * 128;
    const int K = 1024;

    f32x4 acc[4][4];
#pragma unroll
    for (int i = 0; i < 4; i++)
#pragma unroll
        for (int j = 0; j < 4; j++) acc[i][j] = {0.f, 0.f, 0.f, 0.f};

    const int srow = w * 8 + (lane >> 3);
    const int scx = (((lane & 7) ^ ((lane >> 3) & 7)) << 3);
    const short* gA = A + (size_t)(m0 + srow) * K + scx;
    const short* gB = W + (size_t)(n0 + srow) * K + scx;

#pragma unroll
    for (int it = 0; it < 4; it++)
        GLDS(gA + (size_t)it * 32 * K, (char*)As[0] + it * 4096 + w * 1024);
#pragma unroll
    for (int it = 0; it < 4; it++)
        GLDS(gB + (size_t)it * 32 * K, (char*)Bs[0] + it * 4096 + w * 1024);

    for (int t = 0; t < 16; t++) {
        const int c = t & 1;
        if (t < 15) {
            const int k1 = (t + 1) * 64;
#pragma unroll
            for (int it = 0; it < 4; it++)
                GLDS(gA + k1 + (size_t)it * 32 * K, (char*)As[c ^ 1] + it * 4096 + w * 1024);
#pragma unroll
            for (int it = 0; it < 4; it++)
                GLDS(gB + k1 + (size_t)it * 32 * K, (char*)Bs[c ^ 1] + it * 4096 + w * 1024);
            VMC8();
        } else {
            VMC0();
        }
        BARSB();
#pragma unroll
        for (int kk = 0; kk < 2; kk++) {
            bf16x8 a[4], b[4];
#pragma unroll
            for (int mi = 0; mi < 4; mi++)
                a[mi] = *reinterpret_cast<const bf16x8*>(
                    &As[c][(wr * 64 + mi * 16 + lo) * 64 + (((kk * 4 + hi) ^ (lo & 7)) << 3)]);
#pragma unroll
            for (int ni = 0; ni < 4; ni++)
                b[ni] = *reinterpret_cast<const bf16x8*>(
                    &Bs[c][(wc * 64 + ni * 16 + lo) * 64 + (((kk * 4 + hi) ^ (lo & 7)) << 3)]);
#pragma unroll
            for (int mi = 0; mi < 4; mi++)
#pragma unroll
                for (int ni = 0; ni < 4; ni++)
                    acc[mi][ni] = __builtin_amdgcn_mfma_f32_16x16x32_bf16(
                        a[mi], b[ni], acc[mi][ni], 0, 0, 0);
        }
        if (t < 15) BARSB();
    }

#pragma unroll
    for (int mi = 0; mi < 4; mi++) {
#pragma unroll
        for (int r = 0; r < 4; r++) {
            const int m = m0 + wr * 64 + mi * 16 + (hi << 2) + r;
#pragma unroll
            for (int ni = 0; ni < 4; ni++) {
                const int n = n0 + wc * 64 + ni * 16 + lo;
                C[(size_t)m * 1024 + n] = acc[mi][ni][r];
            }
        }
    }
}

extern "C" void kernel_launch(void* const* d_in, const int* in_sizes, int n_in,
                              void* d_out, int out_size, void* d_ws, size_t ws_size,
                              hipStream_t stream) {
    const float* x = (const float*)d_in[0];
    const float* wQKV = (const float*)d_in[1];
    const float* wOut = (const float*)d_in[2];
    const float* cosT = (const float*)d_in[3];
    const float* sinT = (const float*)d_in[4];
    float* out = (float*)d_out;

    char* ws = (char*)d_ws;
    const size_t MB = 1024 * 1024;
    short* xb    = (short*)(ws);             // 8MB
    short* wqkvb = (short*)(ws + 8 * MB);    // 6MB
    short* woutb = (short*)(ws + 14 * MB);   // 2MB
    short* Qbuf  = (short*)(ws + 16 * MB);   // 8MB
    short* Kbuf  = (short*)(ws + 24 * MB);   // 8MB
    short* Vbuf  = (short*)(ws + 32 * MB);   // 8MB
    short* Obuf  = (short*)(ws + 40 * MB);   // 8MB (attn out, bf16)
    float2* csT  = (float2*)(ws + 48 * MB);  // 512KB cos/sin table [32][2048]

    cvt_fused<<<8448, 256, 0, stream>>>(x, wQKV, wOut, cosT, sinT, xb, wqkvb, woutb, csT);
    gemm_qkv_rope<<<256, 512, 0, stream>>>(xb, wqkvb, csT, Qbuf, Kbuf, Vbuf);
    attn_kernel<<<1024, 256, 0, stream>>>(Qbuf, Kbuf, Vbuf, Obuf);
    gemm_out<<<256, 256, 0, stream>>>(Obuf, woutb, out);
}

// Round 25
// 104.455 us; speedup vs baseline: 1.0496x; 1.0219x over previous
//
#include <hip/hip_runtime.h>
#include <hip/hip_bf16.h>

typedef __attribute__((ext_vector_type(8))) short bf16x8;
typedef __attribute__((ext_vector_type(4))) short s16x4;
typedef __attribute__((ext_vector_type(4))) float f32x4;

__device__ __forceinline__ short f2bf(float f) {
    unsigned int u = __builtin_bit_cast(unsigned int, f);
    u += 0x7fffu + ((u >> 16) & 1u);
    return (short)(u >> 16);
}

#define GLDS(g, l) __builtin_amdgcn_global_load_lds( \
    (__attribute__((address_space(1))) void*)(g),    \
    (__attribute__((address_space(3))) void*)(l), 16, 0, 0)

#define BARSB() { __builtin_amdgcn_s_barrier(); __builtin_amdgcn_sched_barrier(0); }
#define VMC8()  { asm volatile("s_waitcnt vmcnt(8)" ::: "memory"); __builtin_amdgcn_sched_barrier(0); }
#define VMC7()  { asm volatile("s_waitcnt vmcnt(7)" ::: "memory"); __builtin_amdgcn_sched_barrier(0); }
#define VMC0()  { asm volatile("s_waitcnt vmcnt(0)" ::: "memory"); __builtin_amdgcn_sched_barrier(0); }

// ------ fused fp32->bf16 convert (x, wQKV, wOut) + cos/sin float2 table build --------
__global__ __launch_bounds__(256) void cvt_fused(const float* __restrict__ x,
                                                 const float* __restrict__ wq,
                                                 const float* __restrict__ wo,
                                                 const float* __restrict__ cosT,
                                                 const float* __restrict__ sinT,
                                                 short* __restrict__ xb,
                                                 short* __restrict__ wqb,
                                                 short* __restrict__ wob,
                                                 float2* __restrict__ csT) {
    const int b = blockIdx.x;
    if (b >= 8192) {
        const int idx = (b - 8192) * 256 + threadIdx.x;   // 0..65535
        const int i2 = idx >> 11;
        const int s = idx & 2047;
        csT[idx] = make_float2(cosT[s * 32 + i2], sinT[s * 32 + i2]);
        return;
    }
    const float* in; short* out; int i;
    if (b < 4096)      { in = x;  out = xb;  i = b * 256 + threadIdx.x; }
    else if (b < 7168) { in = wq; out = wqb; i = (b - 4096) * 256 + threadIdx.x; }
    else               { in = wo; out = wob; i = (b - 7168) * 256 + threadIdx.x; }
    float4 v = reinterpret_cast<const float4*>(in)[i];
    s16x4 r = { f2bf(v.x), f2bf(v.y), f2bf(v.z), f2bf(v.w) };
    reinterpret_cast<s16x4*>(out)[i] = r;
}

#define LDP 72

// ---------------- QKV GEMM (+RoPE), 256x192, loose-wave VMC7 ---------
__device__ __forceinline__ void load_a(const short* __restrict__ A, int wr, int lo, int hi,
                                       int mh, bf16x8 aF[4][2]) {
#pragma unroll
    for (int mi = 0; mi < 4; ++mi)
#pragma unroll
        for (int kk = 0; kk < 2; ++kk)
            aF[mi][kk] = *reinterpret_cast<const bf16x8*>(
                &A[(wr * 128 + mh * 64 + mi * 16 + lo) * 64 + (((kk * 4 + hi) ^ (lo & 7)) << 3)]);
}
__device__ __forceinline__ void load_b3(const short* __restrict__ B, int wc, int lo, int hi,
                                        bf16x8 bF[3][2]) {
#pragma unroll
    for (int ni = 0; ni < 3; ++ni)
#pragma unroll
        for (int kk = 0; kk < 2; ++kk)
            bF[ni][kk] = *reinterpret_cast<const bf16x8*>(
                &B[(wc * 48 + ni * 16 + lo) * 64 + (((kk * 4 + hi) ^ (lo & 7)) << 3)]);
}
__device__ __forceinline__ void mfma24(const bf16x8 aF[4][2], const bf16x8 bF[3][2],
                                       f32x4 acc[8][3], int mh) {
#pragma unroll
    for (int mi = 0; mi < 4; ++mi)
#pragma unroll
        for (int ni = 0; ni < 3; ++ni)
#pragma unroll
            for (int kk = 0; kk < 2; ++kk)
                acc[mh * 4 + mi][ni] = __builtin_amdgcn_mfma_f32_16x16x32_bf16(
                    aF[mi][kk], bF[ni][kk], acc[mh * 4 + mi][ni], 0, 0, 0);
}

__global__ __launch_bounds__(512, 1) void gemm_qkv_rope(
    const short* __restrict__ X, const short* __restrict__ W,
    const float2* __restrict__ csT,
    short* __restrict__ Qo, short* __restrict__ Ko, short* __restrict__ Vo) {
    __shared__ short ldsA[2][16384];
    __shared__ short ldsB[2][12288];
    const int tid = threadIdx.x;
    const int lane = tid & 63;
    const int w = tid >> 6;
    const int lo = lane & 15, hi = lane >> 4;
    const int wr = w >> 2, wc = w & 3;
    const int lin = blockIdx.x;
    const int xcd = lin & 7;
    const int i_ = lin >> 3;
    const int m0 = ((xcd >> 1) * 4 + (i_ & 3)) * 256;
    const int n0 = ((xcd & 1) * 8 + (i_ >> 2)) * 192;

    f32x4 acc[8][3];
#pragma unroll
    for (int i = 0; i < 8; i++)
#pragma unroll
        for (int j = 0; j < 3; j++) acc[i][j] = {0.f, 0.f, 0.f, 0.f};

    const int srow8 = w * 8 + (lane >> 3);
    const int scx = (((lane & 7) ^ ((lane >> 3) & 7)) << 3);

#define STAGE_A(BUF, KT, IT) GLDS(X + (size_t)(m0 + (IT) * 64 + srow8) * 1024 + ((KT) << 6) + scx, \
                                  (char*)&ldsA[BUF][0] + (IT) * 8192 + w * 1024)
#define STAGE_B(BUF, KT, IT) GLDS(W + (size_t)(n0 + (IT) * 64 + srow8) * 1024 + ((KT) << 6) + scx, \
                                  (char*)&ldsB[BUF][0] + (IT) * 8192 + w * 1024)

    bf16x8 aF[4][2], bF[3][2];

    STAGE_B(0, 0, 0); STAGE_B(0, 0, 1); STAGE_B(0, 0, 2);
    STAGE_A(0, 0, 0); STAGE_A(0, 0, 1); STAGE_A(0, 0, 2); STAGE_A(0, 0, 3);

    for (int t = 0; t < 16; ++t) {
        const int c = t & 1;
        if (t < 15) {
            const int nb_ = c ^ 1, t1 = t + 1;
            STAGE_B(nb_, t1, 0); STAGE_B(nb_, t1, 1); STAGE_B(nb_, t1, 2);
            STAGE_A(nb_, t1, 0); STAGE_A(nb_, t1, 1); STAGE_A(nb_, t1, 2); STAGE_A(nb_, t1, 3);
            VMC7();
        } else {
            VMC0();
        }
        BARSB();
        load_a(&ldsA[c][0], wr, lo, hi, 0, aF);
        load_b3(&ldsB[c][0], wc, lo, hi, bF);
        mfma24(aF, bF, acc, 0);
        load_a(&ldsA[c][0], wr, lo, hi, 1, aF);
        mfma24(aF, bF, acc, 1);
        if (t < 15) BARSB();
    }
#undef STAGE_A
#undef STAGE_B

    // ---- RoPE epilogue with coalesced float2 cos/sin table ----
    const int sfull = m0 + wr * 128 + (hi << 2);
    const int b_ = sfull >> 11;
    const int srow_ = sfull & 2047;
#pragma unroll
    for (int ni = 0; ni < 3; ni++) {
        const int n = n0 + wc * 48 + ni * 16 + lo;
        const int region = n >> 10;
        const int c = n & 1023;
        const int h = c >> 6;
        const int d = c & 63;
        const size_t obase = ((size_t)(b_ * 16 + h) * 2048 + srow_) * 64 + d;
        if (region == 2) {
#pragma unroll
            for (int mi = 0; mi < 8; mi++)
#pragma unroll
                for (int r = 0; r < 4; r++)
                    Vo[obase + (size_t)(mi * 16 + r) * 64] = f2bf(acc[mi][ni][r]);
        } else {
            short* dst = (region == 0) ? Qo : Ko;
            const float scale = (region == 0) ? 0.18033688f : 1.0f;  // 1/8 * log2(e)
            const float2* csrow = csT + (size_t)(d >> 1) * 2048 + srow_;
#pragma unroll
            for (int mi = 0; mi < 8; mi++) {
                float4 t0 = *reinterpret_cast<const float4*>(csrow + mi * 16);
                float4 t1 = *reinterpret_cast<const float4*>(csrow + mi * 16 + 2);
                const float cs_[4] = {t0.x, t0.z, t1.x, t1.z};
                const float sn_[4] = {t0.y, t0.w, t1.y, t1.w};
#pragma unroll
                for (int r = 0; r < 4; r++) {
                    float v = acc[mi][ni][r];
                    float other = __shfl_xor(v, 1, 64);
                    float outv = (d & 1) ? (v * cs_[r] + other * sn_[r])
                                         : (v * cs_[r] - other * sn_[r]);
                    dst[obase + (size_t)(mi * 16 + r) * 64] = f2bf(outv * scale);
                }
            }
        }
    }
}

// ---------------- Flash attention (exp2, lazy-max+lazy-l reduce, cvt_pk) -------------
// Both cross-lane reductions are off the common path:
//   - mx: __all() on PER-LANE partial maxes (equivalent: all partials <= bound iff
//     max <= bound); the 2 shfl_xor run only INSIDE the rare rescale branch.
//   - l : kept as per-lane partial, reduced once in the epilogue (alpha is lo-uniform
//     so scaling commutes with the deferred sum).
__device__ __forceinline__ void attn_tile_compute(
    const bf16x8 q0, const bf16x8 q1,
    const short* __restrict__ Ks,          // [64*64] chunk-XOR swizzled
    const short (*Vts)[LDP], short* __restrict__ Pw,
    const int lane, const int w, const bool diag,
    float& m_r, float& l_r, f32x4* __restrict__ o_acc) {
    const int lo = lane & 15, hi = lane >> 4;
    const int sx = lo & 7;

    f32x4 sc[4];
#pragma unroll
    for (int nb = 0; nb < 4; nb++) sc[nb] = {0.f, 0.f, 0.f, 0.f};
#pragma unroll
    for (int nb = 0; nb < 4; nb++) {
        const short* kr = &Ks[(nb * 16 + lo) * 64];
        bf16x8 k0 = *reinterpret_cast<const bf16x8*>(&kr[(hi ^ sx) << 3]);
        sc[nb] = __builtin_amdgcn_mfma_f32_16x16x32_bf16(k0, q0, sc[nb], 0, 0, 0);
        bf16x8 k1 = *reinterpret_cast<const bf16x8*>(&kr[((4 + hi) ^ sx) << 3]);
        sc[nb] = __builtin_amdgcn_mfma_f32_16x16x32_bf16(k1, q1, sc[nb], 0, 0, 0);
    }
    if (diag) {
        const int q_ = w * 16 + lo;
        const int kb = (hi << 2);
#pragma unroll
        for (int nb = 0; nb < 4; nb++) {
            const int k_ = nb * 16 + kb;
#pragma unroll
            for (int r = 0; r < 4; r++)
                if (k_ + r > q_) sc[nb][r] = -1e30f;
        }
    }

    // per-lane partial max only (no cross-lane ops on the common path)
    float mx = sc[0][0];
#pragma unroll
    for (int nb = 0; nb < 4; nb++)
#pragma unroll
        for (int r = 0; r < 4; r++) mx = fmaxf(mx, sc[nb][r]);

    if (!__all(mx <= m_r + 8.0f)) {
        // rare path: full row-max reduction + rescale
        mx = fmaxf(mx, __shfl_xor(mx, 16, 64));
        mx = fmaxf(mx, __shfl_xor(mx, 32, 64));
        const float mnew = fmaxf(m_r, mx);
        const float alpha = __builtin_amdgcn_exp2f(m_r - mnew);   // lo-uniform
        m_r = mnew;
        l_r *= alpha;                                             // per-lane partial: valid
        float aq[4];
#pragma unroll
        for (int r = 0; r < 4; r++) aq[r] = __shfl(alpha, (hi << 2) + r, 64);
#pragma unroll
        for (int db = 0; db < 4; db++)
#pragma unroll
            for (int r = 0; r < 4; r++) o_acc[db][r] *= aq[r];
    }

    float rs = 0.f;
#pragma unroll
    for (int nb = 0; nb < 4; nb++)
#pragma unroll
        for (int r = 0; r < 4; r++) {
            float e = __builtin_amdgcn_exp2f(sc[nb][r] - m_r);
            sc[nb][r] = e;
            rs += e;
        }
    l_r += rs;   // deferred: no cross-lane reduction here

    unsigned int* Pw32 = reinterpret_cast<unsigned int*>(Pw);
#pragma unroll
    for (int nb = 0; nb < 4; nb++)
#pragma unroll
        for (int rr = 0; rr < 2; rr++) {
            unsigned int pk;
            asm("v_cvt_pk_bf16_f32 %0, %1, %2"
                : "=v"(pk) : "v"(sc[nb][2 * rr]), "v"(sc[nb][2 * rr + 1]));
            Pw32[lo * (LDP / 2) + nb * 8 + (hi << 1) + rr] = pk;
        }

#pragma unroll
    for (int kk = 0; kk < 2; kk++) {
        bf16x8 pa = *reinterpret_cast<const bf16x8*>(&Pw[lo * LDP + kk * 32 + hi * 8]);
#pragma unroll
        for (int db = 0; db < 4; db++) {
            const int d = db * 16 + lo;
            const int tsw = (kk * 32 + hi * 8) ^ ((((d >> 3) & 7)) << 3);
            bf16x8 vb = *reinterpret_cast<const bf16x8*>(&Vts[d][tsw]);
            o_acc[db] = __builtin_amdgcn_mfma_f32_16x16x32_bf16(pa, vb, o_acc[db], 0, 0, 0);
        }
    }
}

__global__ __launch_bounds__(256) void attn_kernel(
    const short* __restrict__ Q, const short* __restrict__ K,
    const short* __restrict__ V, short* __restrict__ O) {
    __shared__ short Ks[2][64 * 64];
    __shared__ short Vts[2][64][LDP];
    __shared__ short Ps[4][16 * LDP];

    const int tid = threadIdx.x;
    const int lane = tid & 63;
    const int w = tid >> 6;
    const int lo = lane & 15, hi = lane >> 4;
    const int sx = lo & 7;
    const int lin = blockIdx.x;
    const int bh = lin & 31;
    const int qt = 31 - (lin >> 5);     // LPT: heavy blocks first
    const int b_ = bh >> 4, h = bh & 15;
    const size_t base = (size_t)bh * 2048 * 64;

    const int krow = tid >> 2;
    const int cq = (tid & 3) * 2;
    const int ksw = krow & 7;

    bf16x8 q0, q1;
    {
        const short* src = Q + base + (size_t)(qt * 64 + krow) * 64 + cq * 8;
        bf16x8 a = *reinterpret_cast<const bf16x8*>(src);
        bf16x8 b = *reinterpret_cast<const bf16x8*>(src + 8);
        *reinterpret_cast<bf16x8*>(&Ks[0][krow * 64 + ((cq ^ ksw) << 3)]) = a;
        *reinterpret_cast<bf16x8*>(&Ks[0][krow * 64 + (((cq + 1) ^ ksw) << 3)]) = b;
        __syncthreads();
        q0 = *reinterpret_cast<const bf16x8*>(&Ks[0][(w * 16 + lo) * 64 + ((hi ^ sx) << 3)]);
        q1 = *reinterpret_cast<const bf16x8*>(&Ks[0][(w * 16 + lo) * 64 + (((4 + hi) ^ sx) << 3)]);
        __syncthreads();
    }

    float m_r = -1e30f, l_r = 0.f;
    f32x4 o_acc[4];
#pragma unroll
    for (int db = 0; db < 4; db++) o_acc[db] = {0.f, 0.f, 0.f, 0.f};

    const int u2 = tid >> 3;
    const int vdb8 = (tid & 7) * 8;
    const int vswz = (tid & 7) << 3;
    const int tw = (2 * u2) ^ vswz;

    bf16x8 kr0, kr1, vr0, vr1;
    kr0 = *reinterpret_cast<const bf16x8*>(K + base + (size_t)krow * 64 + cq * 8);
    kr1 = *reinterpret_cast<const bf16x8*>(K + base + (size_t)krow * 64 + cq * 8 + 8);
    vr0 = *reinterpret_cast<const bf16x8*>(V + base + (size_t)(2 * u2) * 64 + vdb8);
    vr1 = *reinterpret_cast<const bf16x8*>(V + base + (size_t)(2 * u2 + 1) * 64 + vdb8);

    int c = 0;
    for (int j = 0; j <= qt; j++) {
        *reinterpret_cast<bf16x8*>(&Ks[c][krow * 64 + ((cq ^ ksw) << 3)]) = kr0;
        *reinterpret_cast<bf16x8*>(&Ks[c][krow * 64 + (((cq + 1) ^ ksw) << 3)]) = kr1;
#pragma unroll
        for (int i = 0; i < 8; i++) {
            unsigned int pv = (unsigned int)(unsigned short)vr0[i] |
                              ((unsigned int)(unsigned short)vr1[i] << 16);
            *reinterpret_cast<unsigned int*>(&Vts[c][vdb8 + i][tw]) = pv;
        }
        __syncthreads();
        if (j < qt) {
            const size_t jb2 = (size_t)(j + 1) * 64;
            kr0 = *reinterpret_cast<const bf16x8*>(K + base + (jb2 + krow) * 64 + cq * 8);
            kr1 = *reinterpret_cast<const bf16x8*>(K + base + (jb2 + krow) * 64 + cq * 8 + 8);
            vr0 = *reinterpret_cast<const bf16x8*>(V + base + (jb2 + 2 * u2) * 64 + vdb8);
            vr1 = *reinterpret_cast<const bf16x8*>(V + base + (jb2 + 2 * u2 + 1) * 64 + vdb8);
        }

        attn_tile_compute(q0, q1, Ks[c], Vts[c], &Ps[w][0], lane, w, j == qt, m_r, l_r, o_acc);
        c ^= 1;
    }

    // finalize deferred l reduction (once per block instead of per tile)
    l_r += __shfl_xor(l_r, 16, 64);
    l_r += __shfl_xor(l_r, 32, 64);

    float inv[4];
#pragma unroll
    for (int r = 0; r < 4; r++) inv[r] = 1.f / __shfl(l_r, (hi << 2) + r, 64);

    short* Op = O + ((size_t)b_ * 2048) * 1024 + (size_t)h * 64;
#pragma unroll
    for (int r = 0; r < 4; r++) {
        const int row = qt * 64 + w * 16 + (hi << 2) + r;
#pragma unroll
        for (int db = 0; db < 4; db++)
            Op[(size_t)row * 1024 + db * 16 + lo] = f2bf(o_acc[db][r] * inv[r]);
    }
}

// ---------------- Out GEMM, 128x128, T2 chunk-swizzle, loose-wave dbuf ---------------
__global__ __launch_bounds__(256) void gemm_out(
    const short* __restrict__ A, const short* __restrict__ W,
    float* __restrict__ C) {
    __shared__ short As[2][128 * 64];
    __shared__ short Bs[2][128 * 64];
    const int tid = threadIdx.x;
    const int lane = tid & 63;
    const int w = tid >> 6;
    const int lo = lane & 15, hi = lane >> 4;
    const int wr = w >> 1, wc = w & 1;
    const int lin = blockIdx.x;
    const int wg = (lin & 7) * 32 + (lin >> 3);
    const int n0 = (wg & 7) * 128;
    const int m0 = (wg >> 3) * 128;
    const int K = 1024;

    f32x4 acc[4][4];
#pragma unroll
    for (int i = 0; i < 4; i++)
#pragma unroll
        for (int j = 0; j < 4; j++) acc[i][j] = {0.f, 0.f, 0.f, 0.f};

    const int srow = w * 8 + (lane >> 3);
    const int scx = (((lane & 7) ^ ((lane >> 3) & 7)) << 3);
    const short* gA = A + (size_t)(m0 + srow) * K + scx;
    const short* gB = W + (size_t)(n0 + srow) * K + scx;

#pragma unroll
    for (int it = 0; it < 4; it++)
        GLDS(gA + (size_t)it * 32 * K, (char*)As[0] + it * 4096 + w * 1024);
#pragma unroll
    for (int it = 0; it < 4; it++)
        GLDS(gB + (size_t)it * 32 * K, (char*)Bs[0] + it * 4096 + w * 1024);

    for (int t = 0; t < 16; t++) {
        const int c = t & 1;
        if (t < 15) {
            const int k1 = (t + 1) * 64;
#pragma unroll
            for (int it = 0; it < 4; it++)
                GLDS(gA + k1 + (size_t)it * 32 * K, (char*)As[c ^ 1] + it * 4096 + w * 1024);
#pragma unroll
            for (int it = 0; it < 4; it++)
                GLDS(gB + k1 + (size_t)it * 32 * K, (char*)Bs[c ^ 1] + it * 4096 + w * 1024);
            VMC8();
        } else {
            VMC0();
        }
        BARSB();
#pragma unroll
        for (int kk = 0; kk < 2; kk++) {
            bf16x8 a[4], b[4];
#pragma unroll
            for (int mi = 0; mi < 4; mi++)
                a[mi] = *reinterpret_cast<const bf16x8*>(
                    &As[c][(wr * 64 + mi * 16 + lo) * 64 + (((kk * 4 + hi) ^ (lo & 7)) << 3)]);
#pragma unroll
            for (int ni = 0; ni < 4; ni++)
                b[ni] = *reinterpret_cast<const bf16x8*>(
                    &Bs[c][(wc * 64 + ni * 16 + lo) * 64 + (((kk * 4 + hi) ^ (lo & 7)) << 3)]);
#pragma unroll
            for (int mi = 0; mi < 4; mi++)
#pragma unroll
                for (int ni = 0; ni < 4; ni++)
                    acc[mi][ni] = __builtin_amdgcn_mfma_f32_16x16x32_bf16(
                        a[mi], b[ni], acc[mi][ni], 0, 0, 0);
        }
        if (t < 15) BARSB();
    }

#pragma unroll
    for (int mi = 0; mi < 4; mi++) {
#pragma unroll
        for (int r = 0; r < 4; r++) {
            const int m = m0 + wr * 64 + mi * 16 + (hi << 2) + r;
#pragma unroll
            for (int ni = 0; ni < 4; ni++) {
                const int n = n0 + wc * 64 + ni * 16 + lo;
                C[(size_t)m * 1024 + n] = acc[mi][ni][r];
            }
        }
    }
}

extern "C" void kernel_launch(void* const* d_in, const int* in_sizes, int n_in,
                              void* d_out, int out_size, void* d_ws, size_t ws_size,
                              hipStream_t stream) {
    const float* x = (const float*)d_in[0];
    const float* wQKV = (const float*)d_in[1];
    const float* wOut = (const float*)d_in[2];
    const float* cosT = (const float*)d_in[3];
    const float* sinT = (const float*)d_in[4];
    float* out = (float*)d_out;

    char* ws = (char*)d_ws;
    const size_t MB = 1024 * 1024;
    short* xb    = (short*)(ws);             // 8MB
    short* wqkvb = (short*)(ws + 8 * MB);    // 6MB
    short* woutb = (short*)(ws + 14 * MB);   // 2MB
    short* Qbuf  = (short*)(ws + 16 * MB);   // 8MB
    short* Kbuf  = (short*)(ws + 24 * MB);   // 8MB
    short* Vbuf  = (short*)(ws + 32 * MB);   // 8MB
    short* Obuf  = (short*)(ws + 40 * MB);   // 8MB (attn out, bf16)
    float2* csT  = (float2*)(ws + 48 * MB);  // 512KB cos/sin table [32][2048]

    cvt_fused<<<8448, 256, 0, stream>>>(x, wQKV, wOut, cosT, sinT, xb, wqkvb, woutb, csT);
    gemm_qkv_rope<<<256, 512, 0, stream>>>(xb, wqkvb, csT, Qbuf, Kbuf, Vbuf);
    attn_kernel<<<1024, 256, 0, stream>>>(Qbuf, Kbuf, Vbuf, Obuf);
    gemm_out<<<256, 256, 0, stream>>>(Obuf, woutb, out);
}